// Round 1
// baseline (159.932 us; speedup 1.0000x reference)
//
#include <hip/hip_runtime.h>

#define IH 512
#define IW 512
#define OH 510
#define OW 510
#define NB 32
#define KO 16

__global__ __launch_bounds__(256) void conv3x3_k16_kernel(
    const float* __restrict__ x,
    const float* __restrict__ k,
    float* __restrict__ out)
{
    // One block per (n, output row i). Thread t -> output cols j=2t, 2t+1.
    const int bid = blockIdx.x;
    const int n = bid / OH;
    const int i = bid - n * OH;
    const int t = threadIdx.x;
    if (t >= OW / 2) return;   // 255 active threads
    const int j = t * 2;

    const float* xr = x + ((size_t)n * IH + i) * IW + j;

    // Load 3 rows x 4 cols of input (all offsets even -> 8B aligned float2)
    float xv[3][4];
#pragma unroll
    for (int r = 0; r < 3; ++r) {
        const float2 a = *reinterpret_cast<const float2*>(xr + r * IW);
        const float2 b = *reinterpret_cast<const float2*>(xr + r * IW + 2);
        xv[r][0] = a.x; xv[r][1] = a.y; xv[r][2] = b.x; xv[r][3] = b.y;
    }

    float* op = out + (((size_t)n * KO) * OH + i) * OW + j;

#pragma unroll
    for (int o = 0; o < KO; ++o) {
        float acc0 = 0.0f, acc1 = 0.0f;
#pragma unroll
        for (int r = 0; r < 3; ++r) {
#pragma unroll
            for (int c = 0; c < 3; ++c) {
                const float kv = k[(o * 3 + r) * 3 + c];  // uniform -> s_load
                acc0 = fmaf(xv[r][c],     kv, acc0);
                acc1 = fmaf(xv[r][c + 1], kv, acc1);
            }
        }
        *reinterpret_cast<float2*>(op + (size_t)o * (OH * OW)) =
            make_float2(acc0, acc1);
    }
}

extern "C" void kernel_launch(void* const* d_in, const int* in_sizes, int n_in,
                              void* d_out, int out_size, void* d_ws, size_t ws_size,
                              hipStream_t stream) {
    const float* x   = (const float*)d_in[0];
    const float* ker = (const float*)d_in[1];
    float* out       = (float*)d_out;

    dim3 grid(NB * OH);   // 16320 blocks, one per (n, output row)
    dim3 block(256);
    conv3x3_k16_kernel<<<grid, block, 0, stream>>>(x, ker, out);
}

// Round 3
// 159.150 us; speedup vs baseline: 1.0049x; 1.0049x over previous
//
#include <hip/hip_runtime.h>

#define IH 512
#define IW 512
#define OH 510
#define OW 510
#define NB 32
#define KO 16

typedef float f32x4 __attribute__((ext_vector_type(4)));
typedef float f32x2 __attribute__((ext_vector_type(2)));

// Block = 256 threads, covers 2 output rows (i0, i0+1) of one image.
// Threads 0-127 -> even row, threads 128-255 -> odd row.
// Full threads compute 4 output cols (float4 store, 16B aligned via per-row
// phase shift); one tail thread per row computes the remaining 2 cols.
__global__ __launch_bounds__(256) void conv3x3_k16_kernel(
    const float* __restrict__ x,
    const float* __restrict__ k,
    float* __restrict__ out)
{
    const int bid = blockIdx.x;
    const int n  = bid / (OH / 2);            // image
    const int i0 = (bid - n * (OH / 2)) * 2;  // even base row
    const int t  = threadIdx.x;
    const int r  = t >> 7;                    // 0: even row, 1: odd row
    const int tt = t & 127;
    const int i  = i0 + r;                    // output row

    const bool tail = (tt == 127);
    // Even rows: j = 4*tt (tail j=508). Odd rows: j = 4*tt+2 (tail j=0).
    // Guarantees (i*OW + j)*4 % 16 == 0 for all full threads.
    int j;
    if (r == 0) j = tail ? 508 : 4 * tt;
    else        j = tail ? 0   : 4 * tt + 2;

    const float* xr = x + ((size_t)n * IH + i) * IW + j;

    // Load 3 rows x 6 cols (tail: 3 x 4). j is even -> float2 8B-aligned.
    float xv[3][6];
#pragma unroll
    for (int rr = 0; rr < 3; ++rr) {
        const float2 a = *reinterpret_cast<const float2*>(xr + rr * IW);
        const float2 b = *reinterpret_cast<const float2*>(xr + rr * IW + 2);
        xv[rr][0] = a.x; xv[rr][1] = a.y; xv[rr][2] = b.x; xv[rr][3] = b.y;
        if (!tail) {
            const float2 c = *reinterpret_cast<const float2*>(xr + rr * IW + 4);
            xv[rr][4] = c.x; xv[rr][5] = c.y;
        } else {
            xv[rr][4] = 0.0f; xv[rr][5] = 0.0f;
        }
    }

    float* op = out + (((size_t)n * KO) * OH + i) * OW + j;

#pragma unroll
    for (int o = 0; o < KO; ++o) {
        float acc0 = 0.0f, acc1 = 0.0f, acc2 = 0.0f, acc3 = 0.0f;
#pragma unroll
        for (int rr = 0; rr < 3; ++rr) {
#pragma unroll
            for (int c = 0; c < 3; ++c) {
                const float kv = k[(o * 3 + rr) * 3 + c];  // uniform -> s_load
                acc0 = fmaf(xv[rr][c],     kv, acc0);
                acc1 = fmaf(xv[rr][c + 1], kv, acc1);
                acc2 = fmaf(xv[rr][c + 2], kv, acc2);
                acc3 = fmaf(xv[rr][c + 3], kv, acc3);
            }
        }
        float* p = op + (size_t)o * (OH * OW);
        if (!tail) {
            f32x4 v; v.x = acc0; v.y = acc1; v.z = acc2; v.w = acc3;
            __builtin_nontemporal_store(v, reinterpret_cast<f32x4*>(p));
        } else {
            f32x2 v; v.x = acc0; v.y = acc1;
            __builtin_nontemporal_store(v, reinterpret_cast<f32x2*>(p));
        }
    }
}

extern "C" void kernel_launch(void* const* d_in, const int* in_sizes, int n_in,
                              void* d_out, int out_size, void* d_ws, size_t ws_size,
                              hipStream_t stream) {
    const float* x   = (const float*)d_in[0];
    const float* ker = (const float*)d_in[1];
    float* out       = (float*)d_out;

    dim3 grid(NB * (OH / 2));   // 8160 blocks, one per (image, row-pair)
    dim3 block(256);
    conv3x3_k16_kernel<<<grid, block, 0, stream>>>(x, ker, out);
}